// Round 1
// baseline (443.382 us; speedup 1.0000x reference)
//
#include <hip/hip_runtime.h>
#include <math.h>

// Problem constants (from reference): x (16,52,256,256) fp32, GROUPS=52, cpg=1
#define Bn 16
#define Gn 52
#define Hn 256
#define Wn 256
#define HW (Hn * Wn)          // 65536
#define HW4 (HW / 4)          // 16384
#define BG (Bn * Gn)          // 832

// workspace layout (floats): [0:BG) qval, [BG:2BG) qrow, [2BG:3BG) qcol,
// [3BG:4BG) gap, [4BG:5BG) mean, [5BG:6BG) weight/(std+1e-5)

// -------- Pass A: per-bg argmax (first occurrence) + mean --------
__global__ __launch_bounds__(256) void k_reduce1(const float4* __restrict__ x4,
                                                 float* __restrict__ ws) {
    const int bg = blockIdx.x;
    const int t = threadIdx.x;
    const size_t base4 = (size_t)bg * HW4;

    float vmax = -INFINITY;
    int imax = 0;
    float sum = 0.f;
    for (int i = t; i < HW4; i += 256) {
        float4 v = x4[base4 + i];
        sum += (v.x + v.y) + (v.z + v.w);
        int e = i * 4;
        if (v.x > vmax) { vmax = v.x; imax = e; }
        if (v.y > vmax) { vmax = v.y; imax = e + 1; }
        if (v.z > vmax) { vmax = v.z; imax = e + 2; }
        if (v.w > vmax) { vmax = v.w; imax = e + 3; }
    }

    __shared__ float sv[256];
    __shared__ int   si[256];
    __shared__ float ss[256];
    sv[t] = vmax; si[t] = imax; ss[t] = sum;
    __syncthreads();
    for (int s = 128; s > 0; s >>= 1) {
        if (t < s) {
            ss[t] += ss[t + s];
            float ov = sv[t + s]; int oi = si[t + s];
            // larger value wins; tie -> smaller index (numpy first occurrence)
            if (ov > sv[t] || (ov == sv[t] && oi < si[t])) { sv[t] = ov; si[t] = oi; }
        }
        __syncthreads();
    }
    if (t == 0) {
        ws[bg]          = sv[0];
        ws[BG + bg]     = (float)(si[0] >> 8);    // idx / W
        ws[2 * BG + bg] = (float)(si[0] & 255);   // idx % W
        ws[3 * BG + bg] = ss[0] * (1.f / (float)HW);
    }
}

// -------- Pass B: per-bg sim statistics (mean, 1/(std+eps) premult weight) --------
__global__ __launch_bounds__(256) void k_stats(const float4* __restrict__ x4,
                                               const float* __restrict__ weight,
                                               const float* __restrict__ one_,
                                               const float* __restrict__ zero,
                                               const float* __restrict__ theta,
                                               const float* __restrict__ scale,
                                               float* __restrict__ ws) {
    const int bg = blockIdx.x;
    const int g = bg % Gn;
    const int t = threadIdx.x;
    const size_t base4 = (size_t)bg * HW4;

    const float qval = ws[bg];
    const float qrow = ws[BG + bg];
    const float qcol = ws[2 * BG + bg];
    const float gap  = ws[3 * BG + bg];
    const float A  = zero[g] * qval;   // coefficient on x*dist
    const float Bc = one_[g] * gap;    // coefficient on x
    const float th0 = theta[0], th1 = theta[1];
    const float sigma = scale[0];
    const float inv2s2 = 0.5f / (sigma * sigma);
    const float lognorm = -logf(sigma) - 0.9189385332046727f; // -0.5*log(2*pi)

    float s1 = 0.f, s2 = 0.f;
    for (int i = t; i < HW4; i += 256) {
        float4 v = x4[base4 + i];
        int e = i * 4;
        float r = (float)(e >> 8);
        float c = (float)(e & 255);
        float zr = (r - qrow) * th0;
        float gr = __expf(lognorm - zr * zr * inv2s2);
        #pragma unroll
        for (int j = 0; j < 4; ++j) {
            float vj = (j == 0) ? v.x : (j == 1) ? v.y : (j == 2) ? v.z : v.w;
            float zc = (c + (float)j - qcol) * th1;
            float gc = __expf(lognorm - zc * zc * inv2s2);
            float dist = 0.5f * (gr + gc);
            float sim = (A * dist + Bc) * vj;
            s1 += sim;
            s2 += sim * sim;
        }
    }

    __shared__ float a1[256];
    __shared__ float a2[256];
    a1[t] = s1; a2[t] = s2;
    __syncthreads();
    for (int s = 128; s > 0; s >>= 1) {
        if (t < s) { a1[t] += a1[t + s]; a2[t] += a2[t + s]; }
        __syncthreads();
    }
    if (t == 0) {
        float S1 = a1[0], S2 = a2[0];
        float mean = S1 * (1.f / (float)HW);
        float var = (S2 - S1 * mean) / (float)(HW - 1);
        var = fmaxf(var, 0.f);
        float std_ = sqrtf(var);
        float inv = 1.f / (std_ + 1e-5f);
        ws[4 * BG + bg] = mean;
        ws[5 * BG + bg] = weight[g] * inv;
    }
}

// -------- Pass C: out = x * sigmoid((sim - mean)*w/(std+eps) + bias) --------
__global__ __launch_bounds__(256) void k_out(const float4* __restrict__ x4,
                                             const float* __restrict__ bias,
                                             const float* __restrict__ one_,
                                             const float* __restrict__ zero,
                                             const float* __restrict__ theta,
                                             const float* __restrict__ scale,
                                             const float* __restrict__ ws,
                                             float4* __restrict__ out4) {
    const int bg = blockIdx.y;
    const int g = bg % Gn;
    const size_t base4 = (size_t)bg * HW4;

    const float qval = ws[bg];
    const float qrow = ws[BG + bg];
    const float qcol = ws[2 * BG + bg];
    const float gap  = ws[3 * BG + bg];
    const float mean = ws[4 * BG + bg];
    const float wsc  = ws[5 * BG + bg];
    const float A  = zero[g] * qval;
    const float Bc = one_[g] * gap;
    const float bb = bias[g];
    const float th0 = theta[0], th1 = theta[1];
    const float sigma = scale[0];
    const float inv2s2 = 0.5f / (sigma * sigma);
    const float lognorm = -logf(sigma) - 0.9189385332046727f;

    int i0 = blockIdx.x * 1024 + threadIdx.x;   // 16 chunks of 1024 float4
    #pragma unroll
    for (int it = 0; it < 4; ++it) {
        int i = i0 + it * 256;
        float4 v = x4[base4 + i];
        int e = i * 4;
        float r = (float)(e >> 8);
        float c = (float)(e & 255);
        float zr = (r - qrow) * th0;
        float gr = __expf(lognorm - zr * zr * inv2s2);
        float4 o;
        #pragma unroll
        for (int j = 0; j < 4; ++j) {
            float vj = (j == 0) ? v.x : (j == 1) ? v.y : (j == 2) ? v.z : v.w;
            float zc = (c + (float)j - qcol) * th1;
            float gc = __expf(lognorm - zc * zc * inv2s2);
            float dist = 0.5f * (gr + gc);
            float sim = (A * dist + Bc) * vj;
            float ctx = (sim - mean) * wsc + bb;
            float sg = __builtin_amdgcn_rcpf(1.0f + __expf(-ctx));
            float oj = vj * sg;
            if (j == 0) o.x = oj; else if (j == 1) o.y = oj; else if (j == 2) o.z = oj; else o.w = oj;
        }
        out4[base4 + i] = o;
    }
}

extern "C" void kernel_launch(void* const* d_in, const int* in_sizes, int n_in,
                              void* d_out, int out_size, void* d_ws, size_t ws_size,
                              hipStream_t stream) {
    const float* x      = (const float*)d_in[0];
    const float* weight = (const float*)d_in[1];
    const float* bias   = (const float*)d_in[2];
    const float* one_   = (const float*)d_in[3];
    const float* zero   = (const float*)d_in[4];
    const float* theta  = (const float*)d_in[5];
    const float* scale  = (const float*)d_in[6];
    float* out = (float*)d_out;
    float* ws  = (float*)d_ws;

    const float4* x4 = (const float4*)x;
    float4* out4 = (float4*)out;

    k_reduce1<<<BG, 256, 0, stream>>>(x4, ws);
    k_stats<<<BG, 256, 0, stream>>>(x4, weight, one_, zero, theta, scale, ws);
    k_out<<<dim3(16, BG), 256, 0, stream>>>(x4, bias, one_, zero, theta, scale, ws, out4);
}

// Round 2
// 407.312 us; speedup vs baseline: 1.0886x; 1.0886x over previous
//
#include <hip/hip_runtime.h>
#include <math.h>

// x: (16, 52, 256, 256) fp32, GROUPS=52, cpg=1. Each (b,g) slice of 65536
// elements is independent: argmax+mean -> sim stats -> gated output.
// One 1024-thread block per slice; the whole 256 KB slice lives in
// registers (16 float4/thread), so x is read from HBM exactly once.
#define Gn 52
#define Hn 256
#define Wn 256
#define HW (Hn * Wn)     // 65536
#define HW4 (HW / 4)     // 16384
#define BG 832
#define TPB 1024
#define VPT 16           // float4 per thread; TPB*VPT == HW4

__global__ __launch_bounds__(TPB) void k_fused(
    const float4* __restrict__ x4,
    const float* __restrict__ weight, const float* __restrict__ bias,
    const float* __restrict__ one_,  const float* __restrict__ zero,
    const float* __restrict__ theta, const float* __restrict__ scale,
    float4* __restrict__ out4)
{
    const int bg   = blockIdx.x;
    const int g    = bg % Gn;
    const int t    = threadIdx.x;
    const int wave = t >> 6;
    const int lane = t & 63;
    const size_t base4 = (size_t)bg * HW4;
    const float4* xp = x4 + base4;

    // ---- load entire slice into registers (coalesced, 16 outstanding) ----
    float4 v[VPT];
    #pragma unroll
    for (int k = 0; k < VPT; ++k) v[k] = xp[t + k * TPB];

    // ---- sweep 1: argmax (first occurrence) + sum ----
    float vmax = -INFINITY; int imax = 0; float sum = 0.f;
    #pragma unroll
    for (int k = 0; k < VPT; ++k) {
        int e = (t + k * TPB) * 4;           // increasing in k -> '>' keeps first
        float4 q = v[k];
        sum += (q.x + q.y) + (q.z + q.w);
        if (q.x > vmax) { vmax = q.x; imax = e; }
        if (q.y > vmax) { vmax = q.y; imax = e + 1; }
        if (q.z > vmax) { vmax = q.z; imax = e + 2; }
        if (q.w > vmax) { vmax = q.w; imax = e + 3; }
    }
    #pragma unroll
    for (int off = 32; off > 0; off >>= 1) {
        float ov = __shfl_down(vmax, off);
        int   oi = __shfl_down(imax, off);
        float os = __shfl_down(sum,  off);
        sum += os;
        // larger wins; tie -> smaller index (numpy first occurrence)
        if (ov > vmax || (ov == vmax && oi < imax)) { vmax = ov; imax = oi; }
    }
    __shared__ float rv[16];
    __shared__ int   ri[16];
    __shared__ float r1[16];
    __shared__ float r2[16];
    __shared__ float bc[6];
    if (lane == 0) { rv[wave] = vmax; ri[wave] = imax; r1[wave] = sum; }
    __syncthreads();
    if (t == 0) {
        float bv = rv[0]; int bi = ri[0]; float bs = r1[0];
        for (int i = 1; i < 16; ++i) {
            bs += r1[i];
            float ov = rv[i]; int oi = ri[i];
            if (ov > bv || (ov == bv && oi < bi)) { bv = ov; bi = oi; }
        }
        bc[0] = bv;                        // qval
        bc[1] = (float)(bi >> 8);          // qrow = idx / W
        bc[2] = (float)(bi & 255);         // qcol = idx % W
        bc[3] = bs * (1.f / (float)HW);    // gap
    }
    __syncthreads();

    const float sigma   = scale[0];
    const float inv2s2  = 0.5f / (sigma * sigma);
    const float lognorm = -logf(sigma) - 0.9189385332046727f; // -0.5*log(2pi)
    const float th0 = theta[0], th1 = theta[1];
    const float qrow = bc[1], qcol = bc[2];
    const float A  = zero[g] * bc[0];      // coeff on x*dist
    const float Bc = one_[g] * bc[3];      // coeff on x

    // ---- sweep 2: sim statistics (values already in registers) ----
    float s1 = 0.f, s2 = 0.f;
    #pragma unroll
    for (int k = 0; k < VPT; ++k) {
        int e = (t + k * TPB) * 4;
        float r = (float)(e >> 8);
        float c = (float)(e & 255);
        float zr = (r - qrow) * th0;
        float gr = __expf(lognorm - zr * zr * inv2s2);
        float4 q = v[k];
        #pragma unroll
        for (int j = 0; j < 4; ++j) {
            float vj = (j == 0) ? q.x : (j == 1) ? q.y : (j == 2) ? q.z : q.w;
            float zc = (c + (float)j - qcol) * th1;
            float gc = __expf(lognorm - zc * zc * inv2s2);
            float sim = (A * (0.5f * (gr + gc)) + Bc) * vj;
            s1 += sim;
            s2 += sim * sim;
        }
    }
    #pragma unroll
    for (int off = 32; off > 0; off >>= 1) {
        s1 += __shfl_down(s1, off);
        s2 += __shfl_down(s2, off);
    }
    if (lane == 0) { r1[wave] = s1; r2[wave] = s2; }
    __syncthreads();
    if (t == 0) {
        float S1 = 0.f, S2 = 0.f;
        for (int i = 0; i < 16; ++i) { S1 += r1[i]; S2 += r2[i]; }
        float mean = S1 * (1.f / (float)HW);
        float var  = (S2 - S1 * mean) * (1.f / (float)(HW - 1));
        var = fmaxf(var, 0.f);
        bc[4] = mean;
        bc[5] = weight[g] / (sqrtf(var) + 1e-5f);
    }
    __syncthreads();
    const float mean = bc[4], wsc = bc[5], bb = bias[g];

    // ---- sweep 3: gated output ----
    #pragma unroll
    for (int k = 0; k < VPT; ++k) {
        int e = (t + k * TPB) * 4;
        float r = (float)(e >> 8);
        float c = (float)(e & 255);
        float zr = (r - qrow) * th0;
        float gr = __expf(lognorm - zr * zr * inv2s2);
        float4 q = v[k], o;
        #pragma unroll
        for (int j = 0; j < 4; ++j) {
            float vj = (j == 0) ? q.x : (j == 1) ? q.y : (j == 2) ? q.z : q.w;
            float zc = (c + (float)j - qcol) * th1;
            float gc = __expf(lognorm - zc * zc * inv2s2);
            float sim = (A * (0.5f * (gr + gc)) + Bc) * vj;
            float ctx = (sim - mean) * wsc + bb;
            float sg  = __builtin_amdgcn_rcpf(1.f + __expf(-ctx));
            float oj  = vj * sg;
            if (j == 0) o.x = oj; else if (j == 1) o.y = oj;
            else if (j == 2) o.z = oj; else o.w = oj;
        }
        out4[base4 + t + k * TPB] = o;
    }
}

extern "C" void kernel_launch(void* const* d_in, const int* in_sizes, int n_in,
                              void* d_out, int out_size, void* d_ws, size_t ws_size,
                              hipStream_t stream) {
    const float* x      = (const float*)d_in[0];
    const float* weight = (const float*)d_in[1];
    const float* bias   = (const float*)d_in[2];
    const float* one_   = (const float*)d_in[3];
    const float* zero   = (const float*)d_in[4];
    const float* theta  = (const float*)d_in[5];
    const float* scale  = (const float*)d_in[6];
    float* out = (float*)d_out;

    k_fused<<<BG, TPB, 0, stream>>>((const float4*)x, weight, bias, one_, zero,
                                    theta, scale, (float4*)out);
}